// Round 8
// baseline (306.215 us; speedup 1.0000x reference)
//
#include <hip/hip_runtime.h>
#include <math.h>
#include <stdint.h>

// MoE: E=8, top-2, D=512, H=2048, N=4096, fp32 in/out.
// Round 13: r9's direct-B-to-VGPR kernel + co-residency (the fix r9 needed).
//   r12 post-mortem: 120us; SQ_LDS_BANK_CONFLICT identical to r11 -> conflicts
//   are in the staging machinery; per block-step LDS moves 52KB (W-DMA 16 +
//   x 4 + ds_read 32) ~ 900cy at measured LDS BW -> LDS traffic + barrier-
//   coupled DMA is the pacer. r9 eliminated exactly that (B straight to VGPR,
//   2 barriers/si) but ran 1 block/CU on a 256-block grid (zero TLP) -- its
//   failure was occupancy, not structure.
//   v13 = r9 kernel (verified correct, absmax 0.00195) re-gridded: SPLIT=2
//   (4 si/block) -> 512 real blocks -> 2 blocks/CU (LDS 48.8KB), bounds(256,2),
//   bf16 y partials (2 hs) in the same ws region. Waves free-run between the
//   2 per-si hT barriers; cross-block TLP hides W-load latency.
//   Fallbacks: mode2 = r8 SPLIT1 f32-y; mode1 = r6; mode0 = fp32.

#define N_TOK 4096
#define D_IN  512
#define H_DIM 2048
#define N_EXP 8
#define TM    32
#define HS    256
#define MAXT  40                // covers cnt up to 1280 (expected ~1024)
#define YROWS (MAXT * TM)       // 1280 y slots per expert
#define HROW  264               // u16 stride: 528B rows, 16B-aligned

typedef float  f32x4  __attribute__((ext_vector_type(4)));
typedef short  short8 __attribute__((ext_vector_type(8)));
typedef short  s16x4  __attribute__((ext_vector_type(4)));
typedef unsigned short u16;

__device__ __forceinline__ u16 bf16_rne(float f) {
    uint32_t u = __float_as_uint(f);
    return (u16)((u + 0x7fffu + ((u >> 16) & 1u)) >> 16);
}
__device__ __forceinline__ float bf16_to_f32(u16 v) {
    return __uint_as_float(((uint32_t)v) << 16);
}
__device__ __forceinline__ void async16(const u16* g, u16* l) {
    __builtin_amdgcn_global_load_lds(
        (const __attribute__((address_space(1))) void*)g,
        (__attribute__((address_space(3))) void*)l, 16, 0, 0);
}

// ---------------------------------------------------------------------------
// Gate body: one wave per token.
// ---------------------------------------------------------------------------
__device__ __forceinline__ void gate_one(
    int n, int l,
    const float* __restrict__ x, const float* __restrict__ Wg,
    const float* __restrict__ bg, float* __restrict__ gates,
    int2* __restrict__ recE, float2* __restrict__ recG,
    u16* __restrict__ xb, int write_xb)
{
    const float* xr  = x + (size_t)n * D_IN + l * 8;
    const float* wgr = Wg + (size_t)l * 8 * N_EXP;

    float xv[8];
    *(float4*)&xv[0] = *(const float4*)xr;
    *(float4*)&xv[4] = *(const float4*)(xr + 4);

    if (write_xb) {
        short8 pk;
#pragma unroll
        for (int i = 0; i < 8; ++i) pk[i] = (short)bf16_rne(xv[i]);
        *(short8*)(xb + (size_t)n * D_IN + l * 8) = pk;
    }

    float acc[8] = {0.f, 0.f, 0.f, 0.f, 0.f, 0.f, 0.f, 0.f};
#pragma unroll
    for (int dd = 0; dd < 8; ++dd) {
        float4 wa = *(const float4*)(wgr + dd * N_EXP);
        float4 wb = *(const float4*)(wgr + dd * N_EXP + 4);
        acc[0] = fmaf(xv[dd], wa.x, acc[0]);
        acc[1] = fmaf(xv[dd], wa.y, acc[1]);
        acc[2] = fmaf(xv[dd], wa.z, acc[2]);
        acc[3] = fmaf(xv[dd], wa.w, acc[3]);
        acc[4] = fmaf(xv[dd], wb.x, acc[4]);
        acc[5] = fmaf(xv[dd], wb.y, acc[5]);
        acc[6] = fmaf(xv[dd], wb.z, acc[6]);
        acc[7] = fmaf(xv[dd], wb.w, acc[7]);
    }
#pragma unroll
    for (int off = 32; off >= 1; off >>= 1) {
#pragma unroll
        for (int e = 0; e < N_EXP; ++e)
            acc[e] += __shfl_xor(acc[e], off);
    }

    float g[8];
    float mx = -3.4e38f;
#pragma unroll
    for (int e = 0; e < N_EXP; ++e) { g[e] = acc[e] + bg[e]; mx = fmaxf(mx, g[e]); }
    float s = 0.f;
#pragma unroll
    for (int e = 0; e < N_EXP; ++e) { g[e] = expf(g[e] - mx); s += g[e]; }
    const float inv = 1.0f / s;
#pragma unroll
    for (int e = 0; e < N_EXP; ++e) g[e] *= inv;

    if (l == 0) {
        float* go = gates + (size_t)n * N_EXP;
        *(float4*)go       = make_float4(g[0], g[1], g[2], g[3]);
        *(float4*)(go + 4) = make_float4(g[4], g[5], g[6], g[7]);

        int e1 = 0; float g1 = g[0];
#pragma unroll
        for (int e = 1; e < N_EXP; ++e) if (g[e] > g1) { g1 = g[e]; e1 = e; }
        int e2 = -1; float g2 = -1.f;
#pragma unroll
        for (int e = 0; e < N_EXP; ++e) if (e != e1 && g[e] > g2) { g2 = g[e]; e2 = e; }

        recE[n] = make_int2(e1, e2);
        recG[n] = make_float2(g1, g2);
    }
}

// ---------------------------------------------------------------------------
// Prep: fused transpose-to-bf16 (blocks < nconv) + gating (blocks >= nconv).
// ---------------------------------------------------------------------------
__global__ __launch_bounds__(256) void moe_prep(
    const float* __restrict__ W1, const float* __restrict__ W2,
    u16* __restrict__ w1t, u16* __restrict__ w2t, int nconv,
    const float* __restrict__ x, const float* __restrict__ Wg,
    const float* __restrict__ bg, float* __restrict__ gates,
    int2* __restrict__ recE, float2* __restrict__ recG,
    u16* __restrict__ xb, int write_xb, int* __restrict__ counts)
{
    __shared__ u16 th[64][65];
    const int idx = blockIdx.x;
    if (idx < nconv) {
        const int z  = idx >> 8;            // 0..15
        const int e  = z & 7;
        const bool isW2 = z >= 8;
        const float* in = isW2 ? W2 : W1;
        u16* ob         = isW2 ? w2t : w1t;
        const int R = isW2 ? H_DIM : D_IN;
        const int C = isW2 ? D_IN : H_DIM;
        const size_t base = (size_t)e * R * C;
        const int rem = idx & 255;
        const int bx = rem & 31, by = rem >> 5;
        const int c0 = (isW2 ? by : bx) * 64;
        const int r0 = (isW2 ? bx : by) * 64;
        const int c  = threadIdx.x & 63, rq = threadIdx.x >> 6;

#pragma unroll
        for (int i = 0; i < 16; ++i) {
            int r = rq * 16 + i;
            th[r][c] = bf16_rne(in[base + (size_t)(r0 + r) * C + c0 + c]);
        }
        __syncthreads();
#pragma unroll
        for (int i = 0; i < 16; ++i) {
            int rw = rq * 16 + i;
            ob[base + (size_t)(c0 + rw) * R + r0 + c] = th[c][rw];
        }
    } else {
        const int g = idx - nconv;
        if (g == 0 && threadIdx.x < N_EXP) counts[threadIdx.x] = 0;
        const int n = g * 4 + (threadIdx.x >> 6);
        const int l = threadIdx.x & 63;
        gate_one(n, l, x, Wg, bg, gates, recE, recG, xb, write_xb);
    }
}

// ---------------------------------------------------------------------------
// List build: 64 blocks (expert e = bid>>3, 512-token chunk).
// ---------------------------------------------------------------------------
__global__ __launch_bounds__(256) void build_lists(
    const int2* __restrict__ recE, const float2* __restrict__ recG,
    int* __restrict__ counts, int* __restrict__ lists, float* __restrict__ cwA,
    int* __restrict__ slotRec)
{
    __shared__ int cnt, base;
    __shared__ int   ltok[512];
    __shared__ float lcw[512];
    __shared__ int   lsrc[512];
    const int e  = blockIdx.x >> 3;
    const int c0 = (blockIdx.x & 7) * 512;
    const int tid = threadIdx.x;
    if (tid == 0) cnt = 0;
    __syncthreads();
#pragma unroll
    for (int it = 0; it < 2; ++it) {
        int t = c0 + it * 256 + tid;
        int2   ee = recE[t];
        float2 gg = recG[t];
        if (ee.x == e) {
            int p = atomicAdd(&cnt, 1);
            ltok[p] = t;  lcw[p] = gg.x;  lsrc[p] = 2 * t;
        }
        if (ee.y == e) {
            int p = atomicAdd(&cnt, 1);
            ltok[p] = t;  lcw[p] = gg.y;  lsrc[p] = 2 * t + 1;
        }
    }
    __syncthreads();
    if (tid == 0) base = atomicAdd(&counts[e], cnt);
    __syncthreads();
    const int c = cnt, b0 = base;
    for (int i = tid; i < c; i += 256) {
        int p = b0 + i;
        lists[e * N_TOK + p] = ltok[i];
        cwA[e * N_TOK + p]   = lcw[i];
        if (slotRec) slotRec[lsrc[i]] = p;
    }
}

#define BARX do { __builtin_amdgcn_s_barrier();                               \
                  __builtin_amdgcn_sched_barrier(0); } while (0)

// ---------------------------------------------------------------------------
// v13 expert kernel: r9 structure (B frags direct global->VGPR; x staged once
// to LDS; hT only other LDS; 2 barriers/si) at SPLIT=2 for 2 blocks/CU.
//   grid = 8 * 2 * MAXT = 640; e=b&7 (XCD affinity); hs=(b>>3)&1; t=b>>4.
//   Per si (4 per block): 32 steps (16 G1 + 16 G2), each {prefetch frag
//   group p+3 to VGPR; 8 MFMA}. LDS: xs 32KB + hT 16.5KB = 48.8KB.
// ---------------------------------------------------------------------------
#define LD1G(base_, ks_, slot_)                                               \
    do {                                                                      \
        _Pragma("unroll")                                                     \
        for (int _nt = 0; _nt < 4; ++_nt)                                     \
            f[slot_][_nt] = *(const short8*)((base_) + off1[_nt] + (ks_) * 32); \
    } while (0)

#define LD2G(base_, u_, slot_)                                                \
    do {                                                                      \
        const int _nc = (u_) >> 2, _k2 = (u_) & 3;                            \
        _Pragma("unroll")                                                     \
        for (int _nt = 0; _nt < 2; ++_nt)                                     \
            _Pragma("unroll")                                                 \
            for (int _kk = 0; _kk < 2; ++_kk)                                 \
                f[slot_][_nt * 2 + _kk] = *(const short8*)((base_) + off2[_nt] \
                    + _nc * 262144 + _k2 * 64 + _kk * 32);                    \
    } while (0)

__global__ __launch_bounds__(256, 2) void moe_expert_v13(
    const u16* __restrict__ xb,
    const u16* __restrict__ w1t, const u16* __restrict__ w2t,
    const float* __restrict__ b1, const float* __restrict__ b2,
    u16* __restrict__ y,
    const int* __restrict__ counts, const int* __restrict__ lists,
    const float* __restrict__ cwA)
{
    const int b  = blockIdx.x;
    const int e  = b & 7;            // expert -> XCD affinity
    const int q  = b >> 3;
    const int hs = q & 1;            // H half (4 si)
    const int t  = q >> 1;           // token tile 0..MAXT-1
    int cnt = counts[e];
    if (cnt > YROWS) cnt = YROWS;
    if (t * TM >= cnt) return;

    __shared__ __align__(16) u16 xs[TM * 512];   // 32 KB, chunk-swizzled
    __shared__ __align__(16) u16 hT[TM * HROW];  // 16.5 KB
    __shared__ int   tokS[TM];
    __shared__ float cwS[TM];

    const int tid  = threadIdx.x;
    const int w    = tid >> 6;
    const int lane = tid & 63;
    const int quad = lane >> 4;
    const int l16  = lane & 15;

    if (tid < TM) {
        int gi = t * TM + tid;
        bool v = gi < cnt;
        tokS[tid] = v ? lists[e * N_TOK + gi] : 0;
        cwS[tid]  = v ? cwA[e * N_TOK + gi] : 0.f;   // cw=0 kills pad rows
    }
    __syncthreads();

    // ---- stage x-tile ONCE: xs[row][512], 16B-chunk swizzle key=(row>>2)&3.
#pragma unroll
    for (int j = 0; j < 8; ++j) {
        const int row = j * 4 + w;
        const u16* src = xb + (size_t)tokS[row] * D_IN
                       + (lane >> 2) * 32 + ((lane & 3) ^ (j & 3)) * 8;
        async16(src, xs + row * 512 + lane * 8);
    }

    // ---- fragment read offsets ----
    int fA1[2], fA2[2];
#pragma unroll
    for (int m = 0; m < 2; ++m) {
        fA1[m] = (m * 16 + l16) * 512 + (quad ^ ((l16 >> 2) & 3)) * 8;
        fA2[m] = (m * 16 + l16) * HROW + quad * 8;
    }

    // ---- direct B-frag global offsets (u16 units) ----
    const u16* w1E = w1t + (size_t)e * H_DIM * D_IN;
    const u16* w2E = w2t + (size_t)e * D_IN * H_DIM;
    int off1[4];
#pragma unroll
    for (int nt = 0; nt < 4; ++nt)
        off1[nt] = (w * 64 + nt * 16 + l16) * 512 + quad * 8;
    int off2[2];
#pragma unroll
    for (int nt = 0; nt < 2; ++nt)
        off2[nt] = (w * 32 + nt * 16 + l16) * 2048 + quad * 8;

    // ---- persistent output accumulator: y[32][512] over this H half ----
    f32x4 accY[4][2][2];
#pragma unroll
    for (int nc = 0; nc < 4; ++nc)
#pragma unroll
        for (int m = 0; m < 2; ++m)
#pragma unroll
            for (int nt = 0; nt < 2; ++nt)
                accY[nc][m][nt] = (f32x4){0.f, 0.f, 0.f, 0.f};

    short8 f[4][4];                 // 4-slot rotating frag buffer (64 VGPR)

    // prologue: prefetch si=hs*4 steps 0..2
    {
        const u16* c10 = w1E + (hs * 4) * (HS * D_IN);
        LD1G(c10, 0, 0);
        LD1G(c10, 1, 1);
        LD1G(c10, 2, 2);
    }
    __syncthreads();                // drains xs staging; xs visible to all

    for (int sq = 0; sq < 4; ++sq) {
        const int si = hs * 4 + sq;
        const u16* c1 = w1E + si * (HS * D_IN);     // G1 slice base
        const u16* c2 = w2E + si * HS;              // G2 col-slice base
        const u16* n1 = c1 + (HS * D_IN);           // next-si G1 base
        float b1v[4];
#pragma unroll
        for (int nt = 0; nt < 4; ++nt)
            b1v[nt] = b1[e * H_DIM + si * HS + w * 64 + nt * 16 + l16];

        f32x4 acc1[2][4];
#pragma unroll
        for (int m = 0; m < 2; ++m)
#pragma unroll
            for (int nt = 0; nt < 4; ++nt) acc1[m][nt] = (f32x4){0.f, 0.f, 0.f, 0.f};

#pragma unroll
        for (int p = 0; p < 32; ++p) {
            const int slot = (p + 3) & 3;
            // prefetch step p+3 (pure global->reg; freely crosses barriers)
            if (p < 13)       { LD1G(c1, p + 3, slot); }
            else if (p < 29)  { LD2G(c2, p - 13, slot); }
            else if (sq < 3)  { LD1G(n1, p - 29, slot); }

            if (p < 16) {
                // ---- G1 step: h-slice += x @ W1T ----
                short8 af0 = *(const short8*)(xs + fA1[0] + p * 32);
                short8 af1 = *(const short8*)(xs + fA1[1] + p * 32);
                __builtin_amdgcn_s_setprio(1);
#pragma unroll
                for (int nt = 0; nt < 4; ++nt) {
                    acc1[0][nt] = __builtin_amdgcn_mfma_f32_16x16x32_bf16(
                        af0, f[p & 3][nt], acc1[0][nt], 0, 0, 0);
                    acc1[1][nt] = __builtin_amdgcn_mfma_f32_16x16x32_bf16(
                        af1, f[p & 3][nt], acc1[1][nt], 0, 0, 0);
                }
                __builtin_amdgcn_s_setprio(0);
            } else {
                if (p == 16) {
                    // hand-off: prev G2 readers done -> write hT -> visible
                    BARX;
#pragma unroll
                    for (int nt = 0; nt < 4; ++nt) {
                        const int c = w * 64 + nt * 16 + l16;
#pragma unroll
                        for (int m = 0; m < 2; ++m)
#pragma unroll
                            for (int r = 0; r < 4; ++r) {
                                int row = m * 16 + quad * 4 + r;
                                hT[row * HROW + c] =
                                    bf16_rne(fmaxf(acc1[m][nt][r] + b1v[nt], 0.f));
                            }
                    }
                    asm volatile("s_waitcnt lgkmcnt(0)" ::: "memory");
                    BARX;
                }
                // ---- G2 step: accY += hT @ W2T ----
                const int u = p - 16, nc = u >> 2, k2 = u & 3;
#pragma unroll
                for (int kk = 0; kk < 2; ++kk) {
                    short8 a0 = *(const short8*)(hT + fA2[0] + k2 * 64 + kk * 32);
                    short8 a1 = *(const short8*)(hT + fA2[1] + k2 * 64 + kk * 32);
                    __builtin_amdgcn_s_setprio(1);
                    accY[nc][0][0] = __builtin_amdgcn_mfma_f32_16x16x32_bf16(
                        a0, f[p & 3][kk],     accY[nc][0][0], 0, 0, 0);
                    accY[nc][1][0] = __builtin_amdgcn_mfma_f32_16x16x32_bf16(
                        a1, f[p & 3][kk],     accY[nc][1][0], 0, 0, 0);
                    accY[nc][0][1] = __builtin_amdgcn_mfma_f32_16x16x32_bf16(
                        a0, f[p & 3][2 + kk], accY[nc][0][1], 0, 0, 0);
                    accY[nc][1][1] = __builtin_amdgcn_mfma_f32_16x16x32_bf16(
                        a1, f[p & 3][2 + kk], accY[nc][1][1], 0, 0, 0);
                    __builtin_amdgcn_s_setprio(0);
                }
            }
        }
    }

    // ---- epilogue: bf16 y partial write: (acc [+b2 at hs0]) * cw ----
    u16* yT = y + (((size_t)e * 2 + hs) * YROWS + (size_t)t * TM) * D_IN;
#pragma unroll
    for (int nc = 0; nc < 4; ++nc)
#pragma unroll
        for (int nt = 0; nt < 2; ++nt) {
            const int dcol = nc * 128 + w * 32 + nt * 16 + l16;
            const float bias = (hs == 0) ? b2[e * D_IN + dcol] : 0.f;
#pragma unroll
            for (int m = 0; m < 2; ++m)
#pragma unroll
                for (int r = 0; r < 4; ++r) {
                    const int row = m * 16 + quad * 4 + r;
                    yT[(size_t)row * D_IN + dcol] =
                        bf16_rne((accY[nc][m][nt][r] + bias) * cwS[row]);
                }
        }
}

// ---------------------------------------------------------------------------
// Combine (mode3): out[t] = sum over k in {1,2}, hs in 0..1 of bf16 partials.
// ---------------------------------------------------------------------------
__global__ __launch_bounds__(256) void moe_combine_b2(
    const u16* __restrict__ y, const int* __restrict__ slotRec,
    const int2* __restrict__ recE, float* __restrict__ out)
{
    const int t  = blockIdx.x * 2 + (threadIdx.x >> 7);
    const int c4 = (threadIdx.x & 127) << 2;
    const int2 ee = recE[t];
    int s1 = slotRec[2 * t + 0];
    int s2 = slotRec[2 * t + 1];
    s1 = s1 < YROWS ? s1 : YROWS - 1;   // safety clamp
    s2 = s2 < YROWS ? s2 : YROWS - 1;
    float acc[4] = {0.f, 0.f, 0.f, 0.f};
#pragma unroll
    for (int h = 0; h < 2; ++h) {
        s16x4 a = *(const s16x4*)(
            y + (((size_t)ee.x * 2 + h) * YROWS + s1) * D_IN + c4);
        s16x4 bb = *(const s16x4*)(
            y + (((size_t)ee.y * 2 + h) * YROWS + s2) * D_IN + c4);
#pragma unroll
        for (int j = 0; j < 4; ++j)
            acc[j] += bf16_to_f32((u16)a[j]) + bf16_to_f32((u16)bb[j]);
    }
    *(float4*)(out + (size_t)t * D_IN + c4) =
        make_float4(acc[0], acc[1], acc[2], acc[3]);
}

// ---------------------------------------------------------------------------
// mode2 fallback: r8 SPLIT=1 TM=32 kernel (known-passing), f32 y.
// ---------------------------------------------------------------------------
#define STG1(si_, ks_, buf_)                                                  \
    do {                                                                      \
        const u16* _s = w1E + (size_t)(si_) * (HS * D_IN) + (ks_) * 32;       \
        _Pragma("unroll")                                                     \
        for (int _i = 0; _i < 4; ++_i)                                        \
            async16(_s + bOffB[_i], &sB[buf_][dstB + _i * 512]);              \
        if (w < 2)                                                            \
            async16(xb + aOffW + (ks_) * 32, &sA[buf_][w * 512 + lane * 8]);  \
    } while (0)

#define STG2(si_, u2_, buf_)                                                  \
    do {                                                                      \
        const int _nc = (u2_) >> 2, _k2 = (u2_) & 3;                          \
        const u16* _s = w2E + (size_t)_nc * (128 * H_DIM) + (si_) * HS + _k2 * 64; \
        _Pragma("unroll")                                                     \
        for (int _i = 0; _i < 4; ++_i)                                        \
            async16(_s + bOff2[_i], &sB[buf_][dstB + _i * 512]);              \
    } while (0)

__global__ __launch_bounds__(256, 2) void moe_expert_mfma2(
    const u16* __restrict__ xb,
    const u16* __restrict__ w1t, const u16* __restrict__ w2t,
    const float* __restrict__ b1, const float* __restrict__ b2,
    float* __restrict__ y,
    const int* __restrict__ counts, const int* __restrict__ lists,
    const float* __restrict__ cwA)
{
    const int b = blockIdx.x;
    const int e = b & 7;
    const int t = b >> 3;
    int cnt = counts[e];
    if (cnt > YROWS) cnt = YROWS;
    if (t * TM >= cnt) return;

    __shared__ __align__(16) u16 sB[3][8192];
    __shared__ __align__(16) u16 sA[3][1024];
    __shared__ __align__(16) u16 hT[TM * HROW];
    __shared__ int   tokS[TM];
    __shared__ float cwS[TM];

    const int tid  = threadIdx.x;
    const int w    = tid >> 6;
    const int lane = tid & 63;
    const int quad = lane >> 4;
    const int l16  = lane & 15;

    if (tid < TM) {
        int gi = t * TM + tid;
        bool v = gi < cnt;
        tokS[tid] = v ? lists[e * N_TOK + gi] : 0;
        cwS[tid]  = v ? cwA[e * N_TOK + gi] : 0.f;
    }
    __syncthreads();

    const int r4   = lane >> 2;
    const int csw1 = (lane & 3) ^ ((lane >> 4) & 3);
    const int r8   = lane >> 3;
    const int csw2 = (lane & 7) ^ r8;
    const int dstB = w * 2048 + lane * 8;

    int fB1[4], fA1[2];
#pragma unroll
    for (int nt = 0; nt < 4; ++nt) {
        int r = w * 64 + nt * 16 + l16;
        fB1[nt] = r * 32 + (quad ^ ((l16 >> 2) & 3)) * 8;
    }
#pragma unroll
    for (int m = 0; m < 2; ++m) {
        int r = m * 16 + l16;
        fA1[m] = r * 32 + (quad ^ ((l16 >> 2) & 3)) * 8;
    }
    int fB2[2][2], fA2[2];
#pragma unroll
    for (int nt = 0; nt < 2; ++nt)
#pragma unroll
        for (int kk = 0; kk < 2; ++kk) {
            int r = w * 32 + nt * 16 + l16;
            fB2[nt][kk] = r * 64 + (((kk * 4 + quad) ^ (l16 & 7)) * 8);
        }
#pragma unroll
    for (int m = 0; m < 2; ++m)
        fA2[m] = (m * 16 + l16) * HROW + quad * 8;

    const u16* w1E = w1t + (size_t)e * H_DIM * D_IN;
    const u16* w2E = w2t + (size_t)e * D_IN * H_DIM;
    int bOffB[4];
#pragma unroll
    for (int i = 0; i < 4; ++i)
        bOffB[i] = (w * 64 + i * 16 + r4) * D_IN + csw1 * 8;
    int bOff2[4];
#pragma unroll
    for (int i = 0; i < 4; ++i)
        bOff2[i] = (w * 32 + i * 8 + r8) * H_DIM + csw2 * 8;
    int aOffW = 0;
    if (w < 2) aOffW = tokS[w * 16 + r4] * D_IN + csw1 * 8;

    f32x4 accY[4][2][2];
#pragma unroll
    for (int nc = 0; nc < 4; ++nc)
#pragma unroll
        for (int m = 0; m < 2; ++m)
#pragma unroll
            for (int nt = 0; nt < 2; ++nt)
                accY[nc][m][nt] = (f32x4){0.f, 0.f, 0.f, 0.f};

    for (int si = 0; si < 8; ++si) {
        float b1v[4];
#pragma unroll
        for (int nt = 0; nt < 4; ++nt)
            b1v[nt] = b1[e * H_DIM + si * HS + w * 64 + nt * 16 + l16];

        STG1(si, 0, 0);

        f32x4 acc1[2][4];
#pragma unroll
        for (int m = 0; m < 2; ++m)
#pragma unroll
            for (int nt = 0; nt < 4; ++nt) acc1[m][nt] = (f32x4){0.f, 0.f, 0.f, 0.f};

#pragma unroll
        for (int u = 0; u < 16; ++u) {
            if (u == 0) {
                asm volatile("s_waitcnt vmcnt(0)" ::: "memory");
            } else if (u < 15) {
                if (w < 2) asm volatile("s_waitcnt vmcnt(5)" ::: "memory");
                else       asm volatile("s_waitcnt vmcnt(4)" ::: "memory");
            } else {
                asm volatile("s_waitcnt vmcnt(4)" ::: "memory");
            }
            BARX;
            if (u == 0)       { STG1(si, 1, 1); STG1(si, 2, 2); }
            else if (u < 14)  { STG1(si, u + 2, (u + 2) % 3); }
            else if (u == 14) { STG2(si, 0, 1); }
            else              { STG2(si, 1, 2); }

            const u16* Bp = &sB[u % 3][0];
            const u16* Ap = &sA[u % 3][0];
            short8 bf[4], af[2];
#pragma unroll
            for (int nt = 0; nt < 4; ++nt) bf[nt] = *(const short8*)(Bp + fB1[nt]);
#pragma unroll
            for (int m = 0; m < 2; ++m)  af[m] = *(const short8*)(Ap + fA1[m]);
            __builtin_amdgcn_s_setprio(1);
#pragma unroll
            for (int nt = 0; nt < 4; ++nt)
#pragma unroll
                for (int m = 0; m < 2; ++m)
                    acc1[m][nt] = __builtin_amdgcn_mfma_f32_16x16x32_bf16(
                        af[m], bf[nt], acc1[m][nt], 0, 0, 0);
            __builtin_amdgcn_s_setprio(0);
        }

#pragma unroll
        for (int nt = 0; nt < 4; ++nt) {
            const int c = w * 64 + nt * 16 + l16;
#pragma unroll
            for (int m = 0; m < 2; ++m)
#pragma unroll
                for (int r = 0; r < 4; ++r) {
                    int row = m * 16 + quad * 4 + r;
                    hT[row * HROW + c] = bf16_rne(fmaxf(acc1[m][nt][r] + b1v[nt], 0.f));
                }
        }

#pragma unroll
        for (int u = 0; u < 16; ++u) {
            if (u == 0)      asm volatile("s_waitcnt vmcnt(4) lgkmcnt(0)" ::: "memory");
            else if (u < 15) asm volatile("s_waitcnt vmcnt(4)" ::: "memory");
            else             asm volatile("s_waitcnt vmcnt(0)" ::: "memory");
            BARX;
            if (u < 14) STG2(si, u + 2, u % 3);

            const int nc = u >> 2, k2 = u & 3;
            const u16* Bp = &sB[(u + 1) % 3][0];
#pragma unroll
            for (int kk = 0; kk < 2; ++kk) {
                short8 a0  = *(const short8*)(hT + fA2[0] + k2 * 64 + kk * 32);
                short8 a1  = *(const short8*)(hT + fA2[1] + k2 * 64 + kk * 32);
                short8 b0  = *(const short8*)(Bp + fB2[0][kk]);
                short8 b1f = *(const short8*)(Bp + fB2[1][kk]);
                __builtin_amdgcn_s_setprio(1);
                accY[nc][0][0] = __builtin_amdgcn_mfma_f32_16x16x32_bf16(a0, b0,  accY[nc][0][0], 0, 0, 0);
                accY[nc][1][0] = __builtin_amdgcn_mfma_f32_16x16x32_bf16(a1, b0,  accY[nc][1][0], 0, 0, 0);
                accY[nc][0][1] = __builtin_amdgcn_mfma_f32_16x16x32_bf16(a0, b1f, accY[nc][0][1], 0, 0, 0);
                accY[nc][1][1] = __builtin_amdgcn_mfma_f32_16x16x32_bf16(a1, b1f, accY[nc][1][1], 0, 0, 0);
                __builtin_amdgcn_s_setprio(0);
            }
        }
    }

    float* yT = y + ((size_t)e * YROWS + (size_t)t * TM) * D_IN;
#pragma unroll
    for (int nc = 0; nc < 4; ++nc)
#pragma unroll
        for (int nt = 0; nt < 2; ++nt) {
            const int dcol = nc * 128 + w * 32 + nt * 16 + l16;
            const float bias = b2[e * D_IN + dcol];
#pragma unroll
            for (int m = 0; m < 2; ++m)
#pragma unroll
                for (int r = 0; r < 4; ++r) {
                    const int row = m * 16 + quad * 4 + r;
                    yT[(size_t)row * D_IN + dcol] =
                        (accY[nc][m][nt][r] + bias) * cwS[row];
                }
        }
}

// ---------------------------------------------------------------------------
// Combine (mode2): out[t] = y[e1][slot1] + y[e2][slot2]  (f32 y).
// ---------------------------------------------------------------------------
__global__ __launch_bounds__(256) void moe_combine_f1(
    const float* __restrict__ y, const int* __restrict__ slotRec,
    const int2* __restrict__ recE, float* __restrict__ out)
{
    const int t  = blockIdx.x * 2 + (threadIdx.x >> 7);
    const int c4 = (threadIdx.x & 127) << 2;
    const int2 ee = recE[t];
    int s1 = slotRec[2 * t + 0];
    int s2 = slotRec[2 * t + 1];
    s1 = s1 < YROWS ? s1 : YROWS - 1;
    s2 = s2 < YROWS ? s2 : YROWS - 1;
    const float4 a  = *(const float4*)(y + ((size_t)ee.x * YROWS + s1) * D_IN + c4);
    const float4 bb = *(const float4*)(y + ((size_t)ee.y * YROWS + s2) * D_IN + c4);
    *(float4*)(out + (size_t)t * D_IN + c4) =
        make_float4(a.x + bb.x, a.y + bb.y, a.z + bb.z, a.w + bb.w);
}

// ---------------------------------------------------------------------------
// r6 single-pass bf16 expert kernel (known-passing) — mode1 fallback.
// ---------------------------------------------------------------------------
__global__ __launch_bounds__(256, 4) void moe_expert_mfma(
    const u16* __restrict__ xb,
    const u16* __restrict__ w1t, const u16* __restrict__ w2t,
    const float* __restrict__ b1, const float* __restrict__ b2,
    float* __restrict__ out,
    const int* __restrict__ counts, const int* __restrict__ lists,
    const float* __restrict__ cwA)
{
    const int b = blockIdx.x;
    const int s = b & 7;
    const int q = b >> 3;
    const int t = q % MAXT;
    const int e = q / MAXT;
    const int cnt = counts[e];
    if (t * TM >= cnt) return;

    __shared__ __align__(16) u16 sB[8192];
    __shared__ __align__(16) u16 sA[1024];
    __shared__ __align__(16) u16 hT[TM * HROW];
    __shared__ int   tokS[TM];
    __shared__ float cwS[TM];

    const int tid  = threadIdx.x;
    const int w    = tid >> 6;
    const int lane = tid & 63;
    const int quad = lane >> 4;
    const int l16  = lane & 15;

    if (tid < TM) {
        int gi = t * TM + tid;
        bool v = gi < cnt;
        tokS[tid] = v ? lists[e * N_TOK + gi] : 0;
        cwS[tid]  = v ? cwA[e * N_TOK + gi] : 0.f;
    }
    __syncthreads();

    const int r4   = lane >> 2;
    const int csw1 = (lane & 3) ^ ((lane >> 4) & 3);
    const int r8   = lane >> 3;
    const int csw2 = (lane & 7) ^ r8;
    u16* ldsB0 = sB + w * 2048 + lane * 8;
    u16* ldsA0 = sA + lane * 8;

    int fB1[4], fA1[2];
#pragma unroll
    for (int nt = 0; nt < 4; ++nt) {
        int r = w * 64 + nt * 16 + l16;
        fB1[nt] = r * 32 + (quad ^ ((l16 >> 2) & 3)) * 8;
    }
#pragma unroll
    for (int m = 0; m < 2; ++m) {
        int r = m * 16 + l16;
        fA1[m] = r * 32 + (quad ^ ((l16 >> 2) & 3)) * 8;
    }
    int fB2[2][2], fA2[2];
#pragma unroll
    for (int nt = 0; nt < 2; ++nt)
#pragma unroll
        for (int kk = 0; kk < 2; ++kk) {
            int r = w * 32 + nt * 16 + l16;
            fB2[nt][kk] = r * 64 + (((kk * 4 + quad) ^ (l16 & 7)) * 8);
        }
#pragma unroll
    for (int m = 0; m < 2; ++m)
        fA2[m] = (m * 16 + l16) * HROW + quad * 8;

    int bOffB[4];
#pragma unroll
    for (int i = 0; i < 4; ++i)
        bOffB[i] = (s * HS + w * 64 + i * 16 + r4) * D_IN + csw1 * 8;
    int aOff0 = tokS[r4]      * D_IN + csw1 * 8;
    int aOff1 = tokS[16 + r4] * D_IN + csw1 * 8;
    const u16* w1E = w1t + (size_t)e * H_DIM * D_IN;

    f32x4 acc1[2][4];
#pragma unroll
    for (int m = 0; m < 2; ++m)
#pragma unroll
        for (int nt = 0; nt < 4; ++nt) acc1[m][nt] = (f32x4){0.f, 0.f, 0.f, 0.f};

    for (int ks = 0; ks < 16; ++ks) {
        const int kb = ks * 32;
        __syncthreads();
#pragma unroll
        for (int i = 0; i < 4; ++i)
            async16(w1E + bOffB[i] + kb, ldsB0 + i * 512);
        if (w == 0) {
            async16(xb + aOff0 + kb, ldsA0);
            async16(xb + aOff1 + kb, ldsA0 + 512);
        }
        __syncthreads();
        short8 bf[4], af[2];
#pragma unroll
        for (int nt = 0; nt < 4; ++nt) bf[nt] = *(const short8*)(sB + fB1[nt]);
#pragma unroll
        for (int m = 0; m < 2; ++m)  af[m] = *(const short8*)(sA + fA1[m]);
#pragma unroll
        for (int nt = 0; nt < 4; ++nt)
#pragma unroll
            for (int m = 0; m < 2; ++m)
                acc1[m][nt] = __builtin_amdgcn_mfma_f32_16x16x32_bf16(af[m], bf[nt], acc1[m][nt], 0, 0, 0);
    }

#pragma unroll
    for (int nt = 0; nt < 4; ++nt) {
        const int c = w * 64 + nt * 16 + l16;
        const float bias = b1[e * H_DIM + s * HS + c];
#pragma unroll
        for (int m = 0; m < 2; ++m)
#pragma unroll
            for (int r = 0; r < 4; ++r) {
                int row = m * 16 + quad * 4 + r;
                hT[row * HROW + c] = bf16_rne(fmaxf(acc1[m][nt][r] + bias, 0.f));
            }
    }

    const u16* w2E = w2t + (size_t)e * D_IN * H_DIM;
    int bOff2[4];
#pragma unroll
    for (int i = 0; i < 4; ++i)
        bOff2[i] = (w * 32 + i * 8 + r8) * H_DIM + s * HS + csw2 * 8;

    for (int nc = 0; nc < 4; ++nc) {
        f32x4 acc2[2][2];
#pragma unroll
        for (int m = 0; m < 2; ++m)
#pragma unroll
            for (int nt = 0; nt < 2; ++nt) acc2[m][nt] = (f32x4){0.f, 0.f, 0.f, 0.f};

        for (int ks = 0; ks < 4; ++ks) {
            __syncthreads();
#pragma unroll
            for (int i = 0; i < 4; ++i)
                async16(w2E + bOff2[i] + nc * (128 * H_DIM) + ks * 64,
                        ldsB0 + i * 512);
            __syncthreads();
#pragma unroll
            for (int kk = 0; kk < 2; ++kk) {
                short8 a0  = *(const short8*)(hT + fA2[0] + ks * 64 + kk * 32);
                short8 a1  = *(const short8*)(hT + fA2[1] + ks * 64 + kk * 32);
                short8 b0  = *(const short8*)(sB + fB2[0][kk]);
                short8 b1f = *(const short8*)(sB + fB2[1][kk]);
                acc2[0][0] = __builtin_amdgcn_mfma_f32_16x16x32_bf16(a0, b0,  acc2[0][0], 0, 0, 0);
                acc2[1][0] = __builtin_amdgcn_mfma_f32_16x16x32_bf16(a1, b0,  acc2[1][0], 0, 0, 0);
                acc2[0][1] = __builtin_amdgcn_mfma_f32_16x16x32_bf16(a0, b1f, acc2[0][1], 0, 0, 0);
                acc2[1][1] = __builtin_amdgcn_mfma_f32_16x16x32_bf16(a1, b1f, acc2[1][1], 0, 0, 0);
            }
        }

#pragma unroll
        for (int nt = 0; nt < 2; ++nt) {
            const int dcol = nc * 128 + w * 32 + nt * 16 + l16;
            const float bias = (s == 0) ? b2[e * D_IN + dcol] : 0.f;
#pragma unroll
            for (int m = 0; m < 2; ++m)
#pragma unroll
                for (int r = 0; r < 4; ++r) {
                    int row = m * 16 + quad * 4 + r;
                    float v = (acc2[m][nt][r] + bias) * cwS[row];
                    atomicAdd(out + (size_t)tokS[row] * D_IN + dcol, v);
                }
        }
    }
}

// ---------------------------------------------------------------------------
// Fallback fp32 expert kernel (round 1, known-passing) — mode0.
// ---------------------------------------------------------------------------
__global__ __launch_bounds__(256, 4) void moe_expert_fp32(
    const float* __restrict__ x,  const float* __restrict__ W1,
    const float* __restrict__ b1, const float* __restrict__ W2,
    const float* __restrict__ b2, float* __restrict__ out,
    const int* __restrict__ counts, const int* __restrict__ lists,
    const float* __restrict__ cwA)
{
    const int e    = blockIdx.x & 7;
    const int tile = blockIdx.x >> 3;
    const int cnt  = counts[e];
    if (tile * 16 >= cnt) return;

    __shared__ float xs[16 * 520];
    __shared__ float hs[16 * 68];
    __shared__ int   tokS[16];
    __shared__ float cwS[16];

    const int tid = threadIdx.x;
    if (tid < 16) {
        int gi = tile * 16 + tid;
        bool v = gi < cnt;
        tokS[tid] = v ? lists[e * N_TOK + gi] : 0;
        cwS[tid]  = v ? cwA[e * N_TOK + gi]  : 0.f;
    }
    __syncthreads();
    {
        const int i = tid >> 4, p = tid & 15;
        const float* xr = x + (size_t)tokS[i] * D_IN + p * 32;
        float* xd = xs + i * 520 + p * 32;
#pragma unroll
        for (int qq = 0; qq < 8; ++qq)
            *(float4*)(xd + qq * 4) = *(const float4*)(xr + qq * 4);
    }
    __syncthreads();

    const float* W1e = W1 + (size_t)e * D_IN * H_DIM;
    const float* W2e = W2 + (size_t)e * H_DIM * D_IN;
    const int j = tid & 31, rg1 = tid >> 5, cg = tid & 63, rg2 = tid >> 6;

    float acc[4][8];
#pragma unroll
    for (int i = 0; i < 4; ++i)
#pragma unroll
        for (int m = 0; m < 8; ++m) acc[i][m] = 0.f;

    for (int hc = 0; hc < H_DIM / 64; ++hc) {
        float a1[2][2] = {{0.f, 0.f}, {0.f, 0.f}};
        const float* w1p = W1e + hc * 64 + j;
        for (int d = 0; d < D_IN; d += 4) {
            float xv[2][4];
            *(float4*)xv[0] = *(const float4*)(xs + (rg1 * 2 + 0) * 520 + d);
            *(float4*)xv[1] = *(const float4*)(xs + (rg1 * 2 + 1) * 520 + d);
#pragma unroll
            for (int dd = 0; dd < 4; ++dd) {
                float wa = w1p[(size_t)(d + dd) * H_DIM];
                float wb = w1p[(size_t)(d + dd) * H_DIM + 32];
                a1[0][0] = fmaf(xv[0][dd], wa, a1[0][0]);
                a1[0][1] = fmaf(xv[0][dd], wb, a1[0][1]);
                a1[1][0] = fmaf(xv[1][dd], wa, a1[1][0]);
                a1[1][1] = fmaf(xv[1][dd], wb, a1[1][1]);
            }
        }
        float b1a = b1[e * H_DIM + hc * 64 + j];
        float b1b = b1[e * H_DIM + hc * 64 + j + 32];
        __syncthreads();
        hs[(rg1 * 2 + 0) * 68 + j]      = fmaxf(a1[0][0] + b1a, 0.f);
        hs[(rg1 * 2 + 0) * 68 + j + 32] = fmaxf(a1[0][1] + b1b, 0.f);
        hs[(rg1 * 2 + 1) * 68 + j]      = fmaxf(a1[1][0] + b1a, 0.f);
        hs[(rg1 * 2 + 1) * 68 + j + 32] = fmaxf(a1[1][1] + b1b, 0.f);
        __syncthreads();
        const float* w2p = W2e + (size_t)(hc * 64) * D_IN + cg;
        for (int k = 0; k < 64; k += 4) {
            float hv[4][4];
#pragma unroll
            for (int i = 0; i < 4; ++i)
                *(float4*)hv[i] = *(const float4*)(hs + (rg2 * 4 + i) * 68 + k);
#pragma unroll
            for (int kk = 0; kk < 4; ++kk) {
                float w2r[8];
#pragma unroll
                for (int m = 0; m < 8; ++m)
                    w2r[m] = w2p[(size_t)(k + kk) * D_IN + 64 * m];
#pragma unroll
                for (int i = 0; i < 4; ++i)
#pragma unroll
                    for (int m = 0; m < 8; ++m)
                        acc[i][m] = fmaf(hv[i][kk], w2r[m], acc[i][m]);
            }
        }
        __syncthreads();
    }
    float b2v[8];
#pragma unroll
    for (int m = 0; m < 8; ++m) b2v[m] = b2[e * D_IN + cg + 64 * m];
#pragma unroll
    for (int i = 0; i < 4; ++i) {
        const int r = rg2 * 4 + i;
        const float cw = cwS[r];
        float* op = out + (size_t)tokS[r] * D_IN + cg;
#pragma unroll
        for (int m = 0; m < 8; ++m)
            atomicAdd(op + 64 * m, (acc[i][m] + b2v[m]) * cw);
    }
}

// ---------------------------------------------------------------------------
extern "C" void kernel_launch(void* const* d_in, const int* in_sizes, int n_in,
                              void* d_out, int out_size, void* d_ws, size_t ws_size,
                              hipStream_t stream) {
    const float* x  = (const float*)d_in[0];
    const float* Wg = (const float*)d_in[1];
    const float* bg = (const float*)d_in[2];
    const float* W1 = (const float*)d_in[3];
    const float* b1 = (const float*)d_in[4];
    const float* W2 = (const float*)d_in[5];
    const float* b2 = (const float*)d_in[6];

    float* out   = (float*)d_out;
    float* gates = out + (size_t)N_TOK * D_IN;

    // ws layout: counts | recE | recG | lists | cw | xb | w1t | w2t | slot | y
    const size_t o_recE  = 1024;
    const size_t o_recG  = o_recE + (size_t)N_TOK * 8;
    const size_t o_lists = o_recG + (size_t)N_TOK * 8;
    const size_t o_cw    = o_lists + (size_t)N_EXP * N_TOK * 4;
    const size_t o_xb    = o_cw + (size_t)N_EXP * N_TOK * 4;
    const size_t o_w1t   = o_xb + (size_t)N_TOK * D_IN * 2;
    const size_t o_w2t   = o_w1t + (size_t)N_EXP * D_IN * H_DIM * 2;
    const size_t o_slot  = o_w2t + (size_t)N_EXP * D_IN * H_DIM * 2;
    const size_t o_y     = o_slot + (size_t)N_TOK * 2 * 4;
    const size_t ybytes1 = (size_t)N_EXP * YROWS * D_IN * 4;         // f32 SPLIT1
    const size_t ybytesb = (size_t)N_EXP * 4 * YROWS * D_IN * 2;     // region cap
    const size_t NEED1   = o_slot;                                   // ~38.1 MB
    const size_t NEED2   = o_y + ybytes1;                            // ~59.1 MB
    const size_t NEED3   = o_y + ybytesb;                            // ~80.1 MB

    int*    counts  = (int*)d_ws;
    int2*   recE    = (int2*)((char*)d_ws + o_recE);
    float2* recG    = (float2*)((char*)d_ws + o_recG);
    int*    lists   = (int*)((char*)d_ws + o_lists);
    float*  cwA     = (float*)((char*)d_ws + o_cw);
    u16*    xb      = (u16*)((char*)d_ws + o_xb);
    u16*    w1t     = (u16*)((char*)d_ws + o_w1t);
    u16*    w2t     = (u16*)((char*)d_ws + o_w2t);
    int*    slotRec = (int*)((char*)d_ws + o_slot);
    float*  ywsF    = (float*)((char*)d_ws + o_y);
    u16*    ywsB    = (u16*)((char*)d_ws + o_y);

    const int mode = (ws_size >= NEED3) ? 3 :
                     (ws_size >= NEED2) ? 2 :
                     (ws_size >= NEED1) ? 1 : 0;
    const int nconv = (mode >= 1) ? 4096 : 0;
    const int nprep = nconv + N_TOK / 4;      // gate: 4 tokens/block, 4 waves

    moe_prep<<<nprep, 256, 0, stream>>>(
        W1, W2, w1t, w2t, nconv,
        x, Wg, bg, gates, recE, recG, xb, mode >= 1 ? 1 : 0, counts);
    build_lists<<<64, 256, 0, stream>>>(recE, recG, counts, lists, cwA,
                                        mode >= 2 ? slotRec : (int*)nullptr);

    if (mode == 3) {
        moe_expert_v13<<<N_EXP * 2 * MAXT, 256, 0, stream>>>(
            xb, w1t, w2t, b1, b2, ywsB, counts, lists, cwA);
        moe_combine_b2<<<N_TOK / 2, 256, 0, stream>>>(ywsB, slotRec, recE, out);
    } else if (mode == 2) {
        moe_expert_mfma2<<<N_EXP * MAXT, 256, 0, stream>>>(
            xb, w1t, w2t, b1, b2, ywsF, counts, lists, cwA);
        moe_combine_f1<<<N_TOK / 2, 256, 0, stream>>>(ywsF, slotRec, recE, out);
    } else if (mode == 1) {
        hipMemsetAsync(d_out, 0, (size_t)N_TOK * D_IN * sizeof(float), stream);
        moe_expert_mfma<<<N_EXP * MAXT * 8, 256, 0, stream>>>(
            xb, w1t, w2t, b1, b2, out, counts, lists, cwA);
    } else {
        hipMemsetAsync(d_out, 0, (size_t)N_TOK * D_IN * sizeof(float), stream);
        moe_expert_fp32<<<N_EXP * 256, 256, 0, stream>>>(
            x, W1, b1, W2, b2, out, counts, lists, cwA);
    }
}